// Round 5
// baseline (745.301 us; speedup 1.0000x reference)
//
#include <hip/hip_runtime.h>

typedef unsigned short u16;
using bf16x8 = __attribute__((ext_vector_type(8))) __bf16;
using f32x4  = __attribute__((ext_vector_type(4))) float;
using u16x8  = __attribute__((ext_vector_type(8))) u16;

__device__ __forceinline__ u16 f2bf(float f) {
    unsigned u = __builtin_bit_cast(unsigned, f);
    u += 0x7FFFu + ((u >> 16) & 1u);           // round-to-nearest-even
    return (u16)(u >> 16);
}
__device__ __forceinline__ float bf2f(u16 h) {
    unsigned u = ((unsigned)h) << 16;
    return __builtin_bit_cast(float, u);
}
__device__ __forceinline__ u16 to_bf(float f) { return f2bf(f); }
__device__ __forceinline__ u16 to_bf(u16 h)   { return h; }

// async global->LDS, 16B per lane; LDS base must be wave-uniform.
__device__ __forceinline__ void gload_lds16(const u16* g, u16* l) {
    __builtin_amdgcn_global_load_lds(
        (const __attribute__((address_space(1))) unsigned int*)g,
        (__attribute__((address_space(3))) unsigned int*)l,
        16, 0, 0);
}

// ---------------- fp32 -> bf16 elementwise (vectorized) ----------------
__global__ __launch_bounds__(256) void k_cvt_f32_bf16(const float* __restrict__ in,
                                                      u16* __restrict__ out, long n) {
    long i = ((long)blockIdx.x * 256 + threadIdx.x) * 8;
    if (i + 8 > n) return;
    f32x4 a = *(const f32x4*)(in + i);
    f32x4 b = *(const f32x4*)(in + i + 4);
    u16x8 o;
    o[0] = f2bf(a[0]); o[1] = f2bf(a[1]); o[2] = f2bf(a[2]); o[3] = f2bf(a[3]);
    o[4] = f2bf(b[0]); o[5] = f2bf(b[1]); o[6] = f2bf(b[2]); o[7] = f2bf(b[3]);
    *(u16x8*)(out + i) = o;
}

// ---------------- tiled transpose (f32->bf16 or bf16->bf16) ----------------
template <typename T>
__global__ __launch_bounds__(256) void k_transpose_bf16(
    const T* __restrict__ in, long in_rs, long in_bs,
    u16* __restrict__ out, long out_rs, long out_bs, int R, int C) {
    __shared__ u16 tile[32][33];
    const int b = blockIdx.z;
    const T* ip = in + (long)b * in_bs;
    u16* op = out + (long)b * out_bs;
    const int tx = threadIdx.x, ty = threadIdx.y;
    const long r0 = (long)blockIdx.y * 32, c0 = (long)blockIdx.x * 32;
#pragma unroll
    for (int i = 0; i < 4; ++i) {
        int r = ty + i * 8;
        tile[r][tx] = to_bf(ip[(r0 + r) * in_rs + c0 + tx]);
    }
    __syncthreads();
#pragma unroll
    for (int i = 0; i < 4; ++i) {
        int c = ty + i * 8;
        op[(c0 + c) * out_rs + r0 + tx] = tile[tx][c];
    }
}

// ---------------- row sum of exp-probs -> reciprocal ----------------
__global__ __launch_bounds__(256) void k_rowsum_recip(const u16* __restrict__ P,
                                                      float* __restrict__ out, int C) {
    const long row = blockIdx.x;
    const u16* p = P + row * (long)C;
    float s = 0.f;
    for (int c = threadIdx.x * 8; c < C; c += 256 * 8) {
        u16x8 v = *(const u16x8*)(p + c);
#pragma unroll
        for (int j = 0; j < 8; ++j) s += bf2f(v[j]);
    }
#pragma unroll
    for (int off = 32; off > 0; off >>= 1) s += __shfl_down(s, off);
    __shared__ float wsum[4];
    const int lane = threadIdx.x & 63, wid = threadIdx.x >> 6;
    if (lane == 0) wsum[wid] = s;
    __syncthreads();
    if (threadIdx.x == 0) out[row] = 1.0f / (wsum[0] + wsum[1] + wsum[2] + wsum[3]);
}

// ========== 256x256 8-phase bf16 GEMM with 1-phase ds_read read-ahead ==========
// C = A * B^T. A: [M][K] (lda), B: [N][K] (ldb). M,N mult of 256, K of 64.
// LDS: [2 buf][2 ksub][256 r][32 k] per operand, st_16x32 swizzle on both sides.
// Per phase: issue NEXT phase's 4/8 ds_reads + 1 staging unit -> s_barrier ->
//   lgkmcnt(count issued THIS phase; prev phase's reads landed) -> 16 MFMA ->
//   [counted vmcnt BEFORE the end barrier, making staging collective] -> s_barrier.
// vmcnt discipline (2 loads/unit): VMC(2) at end of phase 0 retires U2,U3(t);
// VMC(2) at end of phase 2 retires U0,U1(t+1); never 0 in main loop.
// EPI 0: bf16(acc)  1: bf16(exp(acc*scale))  2: bf16(acc*rrow[row])  3: f32(acc+bias[col])

#define LGK(n) asm volatile("s_waitcnt lgkmcnt(" #n ")" ::: "memory")
#define VMC(n) asm volatile("s_waitcnt vmcnt(" #n ")" ::: "memory")
#define SCHB   __builtin_amdgcn_sched_barrier(0)
#define BAR    __builtin_amdgcn_s_barrier()
#define PRIO1  __builtin_amdgcn_s_setprio(1)
#define PRIO0  __builtin_amdgcn_s_setprio(0)

template <int EPI>
__global__ __launch_bounds__(512, 2) void k_gemm8(
    const u16* __restrict__ Ag, long lda, long sA,
    const u16* __restrict__ Bg, long ldb, long sB,
    void* __restrict__ Cv, long ldc, long sC,
    int K, float scale, const float* __restrict__ rrowZ, long sR,
    const float* __restrict__ bias) {
    __shared__ __align__(16) u16 As[2][2][256 * 32];
    __shared__ __align__(16) u16 Bs[2][2][256 * 32];

    const int tid = threadIdx.x;
    const int lane = tid & 63, wid = tid >> 6;
    const int wm = wid >> 2, wn = wid & 3;   // 2(M) x 4(N) wave grid
    const int z = blockIdx.z;
    const long m0 = (long)blockIdx.y * 256;
    const long n0 = (long)blockIdx.x * 256;
    const u16* A = Ag + (long)z * sA;
    const u16* B = Bg + (long)z * sB;

    // staging map: LDS dest linear (unit + (wid*2+c)*1024B + lane*16B);
    // global src pre-swizzled so swizzled ds_reads see logical [r][k].
    int st_idx[2]; long aRow[2], bRow[2];
#pragma unroll
    for (int c = 0; c < 2; ++c) {
        int d_lin = (wid * 2 + c) * 1024 + lane * 16;
        int d_log = d_lin ^ (((d_lin >> 9) & 1) << 5);
        int r = d_log >> 6, kk = (d_log & 63) >> 1;
        st_idx[c] = (wid * 2 + c) * 512;
        aRow[c] = (m0 + r) * lda + kk;
        bRow[c] = (n0 + r) * ldb + kk;
    }
    const int aBase = (wm * 128 + (lane & 15)) * 64 + (lane >> 4) * 16;
    const int bBase = (wn * 64 + (lane & 15)) * 64 + (lane >> 4) * 16;

#define STG_A(pb, ks, kt) do { \
        gload_lds16(A + aRow[0] + (kt) + (ks) * 32, &As[pb][ks][st_idx[0]]); \
        gload_lds16(A + aRow[1] + (kt) + (ks) * 32, &As[pb][ks][st_idx[1]]); } while (0)
#define STG_B(pb, ks, kt) do { \
        gload_lds16(B + bRow[0] + (kt) + (ks) * 32, &Bs[pb][ks][st_idx[0]]); \
        gload_lds16(B + bRow[1] + (kt) + (ks) * 32, &Bs[pb][ks][st_idx[1]]); } while (0)
// load 4 A-fragments (half h: rows h*64..h*64+63 of wave) from ksub ks, buf pb
#define LD4_A(dst, h, ks, pb) do { \
        _Pragma("unroll") for (int _i = 0; _i < 4; ++_i) { \
            int _o = aBase + ((h) * 4 + _i) * 1024; \
            _o ^= ((_o >> 9) & 1) << 5; \
            dst[_i] = *(const bf16x8*)((const char*)&As[pb][ks][0] + _o); } } while (0)
#define LD4_B(dst, ks, pb) do { \
        _Pragma("unroll") for (int _i = 0; _i < 4; ++_i) { \
            int _o = bBase + _i * 1024; \
            _o ^= ((_o >> 9) & 1) << 5; \
            dst[_i] = *(const bf16x8*)((const char*)&Bs[pb][ks][0] + _o); } } while (0)
#define MM16(mb, af, bf) do { \
        _Pragma("unroll") for (int mf = 0; mf < 4; ++mf) \
        _Pragma("unroll") for (int nf = 0; nf < 4; ++nf) \
            acc[(mb) + mf][nf] = __builtin_amdgcn_mfma_f32_16x16x32_bf16( \
                af[mf], bf[nf], acc[(mb) + mf][nf], 0, 0, 0); } while (0)

    f32x4 acc[8][4] = {};
    bf16x8 afrA[4], afrB[4], bfrA[4], bfrB[4];

    // prologue: stage tile 0 (U0=A.k0, U1=B.k0, U2=A.k1, U3=B.k1) into buf 0
    STG_A(0, 0, 0); STG_B(0, 0, 0); STG_A(0, 1, 0); STG_B(0, 1, 0);
    VMC(4);            // own U0,U1 landed; following BAR makes it collective
    BAR; SCHB;
    LD4_A(afrA, 0, 0, 0);   // pre-read phase-0 operands: A.ks0.lo, B.ks0
    LD4_B(bfrA, 0, 0);

    const int NT = K >> 6;
    for (int t = 0; t < NT - 1; ++t) {
        const int p = t & 1;
        const long ktn = (long)(t + 1) * 64;
        // phase 0: MFMA(lo,ks0); read-ahead A.ks0.hi; stage U0(t+1);
        //          end: VM2 retires U2,U3(t) -> BAR makes collective for phase 1
        LD4_A(afrB, 1, 0, p);
        STG_A(p ^ 1, 0, ktn);
        BAR; LGK(4); SCHB;
        PRIO1; MM16(0, afrA, bfrA); PRIO0;
        VMC(2); SCHB;
        BAR;
        // phase 1: MFMA(hi,ks0); read A.ks1.lo + B.ks1 (U2,U3 now collective)
        LD4_A(afrA, 0, 1, p);
        LD4_B(bfrB, 1, p);
        STG_B(p ^ 1, 0, ktn);
        BAR; LGK(8); SCHB;
        PRIO1; MM16(4, afrB, bfrA); PRIO0;
        BAR;
        // phase 2: MFMA(lo,ks1); read-ahead A.ks1.hi; stage U2(t+1);
        //          end: VM2 retires U0,U1(t+1) -> collective for phase 3
        LD4_A(afrB, 1, 1, p);
        STG_A(p ^ 1, 1, ktn);
        BAR; LGK(4); SCHB;
        PRIO1; MM16(0, afrA, bfrB); PRIO0;
        VMC(2); SCHB;
        BAR;
        // phase 3: MFMA(hi,ks1); read next tile's A.ks0.lo + B.ks0 from buf p^1
        LD4_A(afrA, 0, 0, p ^ 1);
        LD4_B(bfrA, 0, p ^ 1);
        STG_B(p ^ 1, 1, ktn);
        BAR; LGK(8); SCHB;
        PRIO1; MM16(4, afrB, bfrB); PRIO0;
        BAR;
    }
    {   // final tile, no staging
        const int p = (NT - 1) & 1;
        // phase 0; end: drain remaining staging (U2,U3 of this tile)
        LD4_A(afrB, 1, 0, p);
        BAR; LGK(4); SCHB;
        PRIO1; MM16(0, afrA, bfrA); PRIO0;
        VMC(0); SCHB;
        BAR;
        // phase 1
        LD4_A(afrA, 0, 1, p);
        LD4_B(bfrB, 1, p);
        BAR; LGK(8); SCHB;
        PRIO1; MM16(4, afrB, bfrA); PRIO0;
        BAR;
        // phase 2
        LD4_A(afrB, 1, 1, p);
        BAR; LGK(4); SCHB;
        PRIO1; MM16(0, afrA, bfrB); PRIO0;
        BAR;
        // phase 3
        LGK(0); SCHB;
        PRIO1; MM16(4, afrB, bfrB); PRIO0;
    }

    // epilogue. C/D layout: col = lane&15, row = (lane>>4)*4 + j
    const int r_in = (lane >> 4) * 4;
    const int c_in = lane & 15;
    const float* rr = (EPI == 2) ? (rrowZ + (long)z * sR) : nullptr;
#pragma unroll
    for (int mf = 0; mf < 8; ++mf) {
#pragma unroll
        for (int nf = 0; nf < 4; ++nf) {
            const long cg = n0 + wn * 64 + nf * 16 + c_in;
#pragma unroll
            for (int j = 0; j < 4; ++j) {
                const long rg = m0 + wm * 128 + mf * 16 + r_in + j;
                float v = acc[mf][nf][j];
                if constexpr (EPI == 0) {
                    ((u16*)Cv)[(long)z * sC + rg * ldc + cg] = f2bf(v);
                } else if constexpr (EPI == 1) {
                    ((u16*)Cv)[(long)z * sC + rg * ldc + cg] = f2bf(__expf(v * scale));
                } else if constexpr (EPI == 2) {
                    ((u16*)Cv)[(long)z * sC + rg * ldc + cg] = f2bf(v * rr[rg]);
                } else {
                    ((float*)Cv)[(long)z * sC + rg * ldc + cg] = v + bias[cg];
                }
            }
        }
    }
#undef MM16
#undef LD4_A
#undef LD4_B
#undef STG_A
#undef STG_B
}

extern "C" void kernel_launch(void* const* d_in, const int* in_sizes, int n_in,
                              void* d_out, int out_size, void* d_ws, size_t ws_size,
                              hipStream_t stream) {
    (void)in_sizes; (void)n_in; (void)out_size;
    const int S = 4096;
    const long BS = 4L * S;  // 16384 tokens
    const float* x_f    = (const float*)d_in[0];  // [BS][2048]
    const float* Wqkv_f = (const float*)d_in[1];  // [2048][3072]
    const float* Wff_f  = (const float*)d_in[2];  // [1024][1024]
    const float* bff    = (const float*)d_in[3];  // [1024]
    float* out = (float*)d_out;                   // [BS][1024]

    // batched attention (z=4) needs 4x probs; fall back if ws too small
    const size_t need4 = 67108864UL + 12582912UL + 2097152UL + 100663296UL +
                         33554432UL + 4UL * 33554432UL + 33554432UL + 65536UL;
    const bool batched = ws_size >= need4;
    const int Z = batched ? 4 : 1;

    char* p = (char*)d_ws;
    u16* x_bf  = (u16*)p; p += BS * 2048 * 2;
    u16* WqkvT = (u16*)p; p += 3072L * 2048 * 2;
    u16* WffT  = (u16*)p; p += 1024L * 1024 * 2;
    u16* kqv   = (u16*)p; p += BS * 3072 * 2;
    u16* vT    = (u16*)p; p += 4L * 1024 * 4096 * 2;
    u16* probs = (u16*)p; p += (long)Z * 4096L * 4096 * 2;
    u16* attn  = (u16*)p; p += BS * 1024 * 2;
    float* rrow = (float*)p; p += (long)Z * 4096L * 4;

    // 1. conversions / weight transposes
    k_cvt_f32_bf16<<<dim3((unsigned)(BS * 2048 / 2048)), 256, 0, stream>>>(x_f, x_bf, BS * 2048);
    k_transpose_bf16<float><<<dim3(3072 / 32, 2048 / 32, 1), dim3(32, 8), 0, stream>>>(
        Wqkv_f, 3072, 0, WqkvT, 2048, 0, 2048, 3072);
    k_transpose_bf16<float><<<dim3(1024 / 32, 1024 / 32, 1), dim3(32, 8), 0, stream>>>(
        Wff_f, 1024, 0, WffT, 1024, 0, 1024, 1024);

    // 2. kqv = X @ W_qkv   [16384 x 3072], K=2048
    k_gemm8<0><<<dim3(3072 / 256, 16384 / 256, 1), 512, 0, stream>>>(
        x_bf, 2048, 0, WqkvT, 2048, 0, kqv, 3072, 0, 2048, 0.f, nullptr, 0, nullptr);

    // 3. transpose V (cols [2048,3072) of kqv) to [4][1024][4096]
    k_transpose_bf16<u16><<<dim3(1024 / 32, 4096 / 32, 4), dim3(32, 8), 0, stream>>>(
        kqv + 2048, 3072, (long)S * 3072, vT, 4096, 1024L * 4096, 4096, 1024);

    // 4. attention: probs = exp(Q K^T * scale); attn = (probs @ V) * (1/rowsum)
    const float scale = 0.08838834764831845f;  // 1/sqrt(128)
    for (int b = 0; b < 4; b += Z) {
        const u16* kbase = kqv + (long)b * S * 3072;  // k at +0, q at +1024
        k_gemm8<1><<<dim3(4096 / 256, 4096 / 256, Z), 512, 0, stream>>>(
            kbase + 1024, 3072, (long)S * 3072, kbase, 3072, (long)S * 3072,
            probs, 4096, (long)S * S, 1024, scale, nullptr, 0, nullptr);
        k_rowsum_recip<<<Z * 4096, 256, 0, stream>>>(probs, rrow, 4096);
        k_gemm8<2><<<dim3(1024 / 256, 4096 / 256, Z), 512, 0, stream>>>(
            probs, 4096, (long)S * S, vT + (long)b * 1024 * 4096, 4096, 1024L * 4096,
            attn + (long)b * S * 1024, 1024, (long)S * 1024,
            4096, 0.f, rrow, 4096, nullptr);
    }

    // 5. out = attn @ W_ff + b_ff  (fp32 output)
    k_gemm8<3><<<dim3(1024 / 256, 16384 / 256, 1), 512, 0, stream>>>(
        attn, 1024, 0, WffT, 1024, 0, out, 1024, 0, 1024, 0.f, nullptr, 0, bff);
}

// Round 6
// 619.134 us; speedup vs baseline: 1.2038x; 1.2038x over previous
//
#include <hip/hip_runtime.h>

typedef unsigned short u16;
using bf16x8 = __attribute__((ext_vector_type(8))) __bf16;
using f32x4  = __attribute__((ext_vector_type(4))) float;
using u16x8  = __attribute__((ext_vector_type(8))) u16;

__device__ __forceinline__ u16 f2bf(float f) {
    unsigned u = __builtin_bit_cast(unsigned, f);
    u += 0x7FFFu + ((u >> 16) & 1u);           // round-to-nearest-even
    return (u16)(u >> 16);
}
__device__ __forceinline__ float bf2f(u16 h) {
    unsigned u = ((unsigned)h) << 16;
    return __builtin_bit_cast(float, u);
}
__device__ __forceinline__ u16 to_bf(float f) { return f2bf(f); }
__device__ __forceinline__ u16 to_bf(u16 h)   { return h; }

// async global->LDS, 16B per lane; LDS base must be wave-uniform.
__device__ __forceinline__ void gload_lds16(const u16* g, u16* l) {
    __builtin_amdgcn_global_load_lds(
        (const __attribute__((address_space(1))) unsigned int*)g,
        (__attribute__((address_space(3))) unsigned int*)l,
        16, 0, 0);
}

// ---------------- fp32 -> bf16 elementwise (vectorized) ----------------
__global__ __launch_bounds__(256) void k_cvt_f32_bf16(const float* __restrict__ in,
                                                      u16* __restrict__ out, long n) {
    long i = ((long)blockIdx.x * 256 + threadIdx.x) * 8;
    if (i + 8 > n) return;
    f32x4 a = *(const f32x4*)(in + i);
    f32x4 b = *(const f32x4*)(in + i + 4);
    u16x8 o;
    o[0] = f2bf(a[0]); o[1] = f2bf(a[1]); o[2] = f2bf(a[2]); o[3] = f2bf(a[3]);
    o[4] = f2bf(b[0]); o[5] = f2bf(b[1]); o[6] = f2bf(b[2]); o[7] = f2bf(b[3]);
    *(u16x8*)(out + i) = o;
}

// ---------------- tiled transpose (f32->bf16 or bf16->bf16) ----------------
template <typename T>
__global__ __launch_bounds__(256) void k_transpose_bf16(
    const T* __restrict__ in, long in_rs, long in_bs,
    u16* __restrict__ out, long out_rs, long out_bs, int R, int C) {
    __shared__ u16 tile[32][33];
    const int b = blockIdx.z;
    const T* ip = in + (long)b * in_bs;
    u16* op = out + (long)b * out_bs;
    const int tx = threadIdx.x, ty = threadIdx.y;
    const long r0 = (long)blockIdx.y * 32, c0 = (long)blockIdx.x * 32;
#pragma unroll
    for (int i = 0; i < 4; ++i) {
        int r = ty + i * 8;
        tile[r][tx] = to_bf(ip[(r0 + r) * in_rs + c0 + tx]);
    }
    __syncthreads();
#pragma unroll
    for (int i = 0; i < 4; ++i) {
        int c = ty + i * 8;
        op[(c0 + c) * out_rs + r0 + tx] = tile[tx][c];
    }
}

// ---------------- row sum of exp-probs -> reciprocal ----------------
__global__ __launch_bounds__(256) void k_rowsum_recip(const u16* __restrict__ P,
                                                      float* __restrict__ out, int C) {
    const long row = blockIdx.x;
    const u16* p = P + row * (long)C;
    float s = 0.f;
    for (int c = threadIdx.x * 8; c < C; c += 256 * 8) {
        u16x8 v = *(const u16x8*)(p + c);
#pragma unroll
        for (int j = 0; j < 8; ++j) s += bf2f(v[j]);
    }
#pragma unroll
    for (int off = 32; off > 0; off >>= 1) s += __shfl_down(s, off);
    __shared__ float wsum[4];
    const int lane = threadIdx.x & 63, wid = threadIdx.x >> 6;
    if (lane == 0) wsum[wid] = s;
    __syncthreads();
    if (threadIdx.x == 0) out[row] = 1.0f / (wsum[0] + wsum[1] + wsum[2] + wsum[3]);
}

// ====== 128x256 bf16 GEMM, BK=32, 3-buffer ring, 2 blocks/CU, C = A*B^T ======
// A: [M][K] (lda), B: [N][K] (ldb). M mult of 128, N of 256, K of 32 (NT>=3).
// 8 waves (2M x 4N), per-wave 64x64 output (acc 4x4 f32x4 = 64 VGPR).
// LDS: As[3][128*32] + Bs[3][256*32] = 72 KB -> 2 blocks/CU with <=128 VGPR
// (__launch_bounds__(512,4)). Swizzle byte ^= ((byte>>9)&1)<<5 on both sides
// (16B-alignment-safe; measured 0 bank conflicts with this read pattern).
// Per tile: 8 ds_read_b128 (frags, buf b0) + stage tile t+2 into b2 (3 gloads)
//   -> lgkmcnt(0) -> 16 MFMA -> vmcnt(3) [tail: vmcnt(0)] -> s_barrier.
// vmcnt(3): retires tile t+1's 3 loads, leaves t+2's 3 in flight (never 0
// in steady state). One barrier per tile; co-resident block fills stalls.
// EPI 0: bf16(acc)  1: bf16(exp(acc*scale))  2: bf16(acc*rrow[row])  3: f32(acc+bias[col])

#define LGK(n) asm volatile("s_waitcnt lgkmcnt(" #n ")" ::: "memory")
#define VMC(n) asm volatile("s_waitcnt vmcnt(" #n ")" ::: "memory")
#define SCHB   __builtin_amdgcn_sched_barrier(0)
#define BAR    __builtin_amdgcn_s_barrier()
#define PRIO1  __builtin_amdgcn_s_setprio(1)
#define PRIO0  __builtin_amdgcn_s_setprio(0)
#define SWZ(b) ((b) ^ ((((b) >> 9) & 1) << 5))

template <int EPI>
__global__ __launch_bounds__(512, 4) void k_gemm3b(
    const u16* __restrict__ Ag, long lda, long sA,
    const u16* __restrict__ Bg, long ldb, long sB,
    void* __restrict__ Cv, long ldc, long sC,
    int K, float scale, const float* __restrict__ rrowZ, long sR,
    const float* __restrict__ bias) {
    __shared__ __align__(16) u16 As[3][128 * 32];
    __shared__ __align__(16) u16 Bs[3][256 * 32];

    const int tid = threadIdx.x;
    const int lane = tid & 63, wid = tid >> 6;
    const int wm = wid >> 2, wn = wid & 3;   // 2(M) x 4(N) wave grid
    const int z = blockIdx.z;
    const long m0 = (long)blockIdx.y * 128;
    const long n0 = (long)blockIdx.x * 256;
    const u16* A = Ag + (long)z * sA;
    const u16* B = Bg + (long)z * sB;

    // staging sources (linear LDS dest; pre-swizzled global src).
    // A unit 8 KB: 1 load/thread; B unit 16 KB: 2 loads/thread.
    long aSrc, bSrc0, bSrc1;
    {
        int dg = SWZ(tid * 16);
        aSrc = (m0 + (dg >> 6)) * lda + ((dg & 63) >> 1);
        dg = SWZ(tid * 16);                 // c=0 (offsets <8192: same formula)
        bSrc0 = (n0 + (dg >> 6)) * ldb + ((dg & 63) >> 1);
        dg = SWZ(8192 + tid * 16);          // c=1
        bSrc1 = (n0 + (dg >> 6)) * ldb + ((dg & 63) >> 1);
    }
    const int r16 = lane & 15, g = lane >> 4;
    const int vA = SWZ((wm * 64 + r16) * 64 + g * 16);   // byte off in A buf
    const int vB = SWZ((wn * 64 + r16) * 64 + g * 16);   // byte off in B buf

#define STG(bb, kt) do { \
        gload_lds16(A + aSrc + (kt), &As[bb][wid * 512]); \
        gload_lds16(B + bSrc0 + (kt), &Bs[bb][wid * 512]); \
        gload_lds16(B + bSrc1 + (kt), &Bs[bb][4096 + wid * 512]); } while (0)
#define LD4_A(bb) do { _Pragma("unroll") for (int _i = 0; _i < 4; ++_i) \
        afr[_i] = *(const bf16x8*)((const char*)&As[bb][0] + vA + _i * 1024); } while (0)
#define LD4_B(bb) do { _Pragma("unroll") for (int _i = 0; _i < 4; ++_i) \
        bfr[_i] = *(const bf16x8*)((const char*)&Bs[bb][0] + vB + _i * 1024); } while (0)
#define MM16() do { \
        _Pragma("unroll") for (int mf = 0; mf < 4; ++mf) \
        _Pragma("unroll") for (int nf = 0; nf < 4; ++nf) \
            acc[mf][nf] = __builtin_amdgcn_mfma_f32_16x16x32_bf16( \
                afr[mf], bfr[nf], acc[mf][nf], 0, 0, 0); } while (0)

    f32x4 acc[4][4] = {};
    bf16x8 afr[4], bfr[4];

    const int NT = K >> 5;   // K-tiles of 32; NT >= 3 assumed
    // prologue: stage tiles 0 and 1
    STG(0, 0); STG(1, 32);
    VMC(3); SCHB;            // tile 0's 3 loads landed (own); BAR -> collective
    BAR; SCHB;

    int b0 = 0, b1 = 1, b2 = 2;
    for (int t = 0; t < NT; ++t) {
        LD4_A(b0); LD4_B(b0);                       // 8 ds_read_b128
        if (t + 2 < NT) STG(b2, (long)(t + 2) * 32);
        LGK(0); SCHB;
        PRIO1; MM16(); PRIO0;
        if (t + 2 < NT) { VMC(3); }                 // retire tile t+1's loads
        else if (t + 1 < NT) { VMC(0); }            // tail drain
        SCHB; BAR; SCHB;
        int tm = b0; b0 = b1; b1 = b2; b2 = tm;
    }

    // epilogue. C/D layout: col = lane&15, row = (lane>>4)*4 + j
    const int r_in = (lane >> 4) * 4;
    const int c_in = lane & 15;
    const float* rr = (EPI == 2) ? (rrowZ + (long)z * sR) : nullptr;
#pragma unroll
    for (int mf = 0; mf < 4; ++mf) {
#pragma unroll
        for (int nf = 0; nf < 4; ++nf) {
            const long cg = n0 + wn * 64 + nf * 16 + c_in;
#pragma unroll
            for (int j = 0; j < 4; ++j) {
                const long rg = m0 + wm * 64 + mf * 16 + r_in + j;
                float v = acc[mf][nf][j];
                if constexpr (EPI == 0) {
                    ((u16*)Cv)[(long)z * sC + rg * ldc + cg] = f2bf(v);
                } else if constexpr (EPI == 1) {
                    ((u16*)Cv)[(long)z * sC + rg * ldc + cg] = f2bf(__expf(v * scale));
                } else if constexpr (EPI == 2) {
                    ((u16*)Cv)[(long)z * sC + rg * ldc + cg] = f2bf(v * rr[rg]);
                } else {
                    ((float*)Cv)[(long)z * sC + rg * ldc + cg] = v + bias[cg];
                }
            }
        }
    }
#undef MM16
#undef LD4_A
#undef LD4_B
#undef STG
}

extern "C" void kernel_launch(void* const* d_in, const int* in_sizes, int n_in,
                              void* d_out, int out_size, void* d_ws, size_t ws_size,
                              hipStream_t stream) {
    (void)in_sizes; (void)n_in; (void)out_size;
    const int S = 4096;
    const long BS = 4L * S;  // 16384 tokens
    const float* x_f    = (const float*)d_in[0];  // [BS][2048]
    const float* Wqkv_f = (const float*)d_in[1];  // [2048][3072]
    const float* Wff_f  = (const float*)d_in[2];  // [1024][1024]
    const float* bff    = (const float*)d_in[3];  // [1024]
    float* out = (float*)d_out;                   // [BS][1024]

    // batched attention (z=4) needs 4x probs; fall back if ws too small
    const size_t need4 = 67108864UL + 12582912UL + 2097152UL + 100663296UL +
                         33554432UL + 4UL * 33554432UL + 33554432UL + 65536UL;
    const bool batched = ws_size >= need4;
    const int Z = batched ? 4 : 1;

    char* p = (char*)d_ws;
    u16* x_bf  = (u16*)p; p += BS * 2048 * 2;
    u16* WqkvT = (u16*)p; p += 3072L * 2048 * 2;
    u16* WffT  = (u16*)p; p += 1024L * 1024 * 2;
    u16* kqv   = (u16*)p; p += BS * 3072 * 2;
    u16* vT    = (u16*)p; p += 4L * 1024 * 4096 * 2;
    u16* probs = (u16*)p; p += (long)Z * 4096L * 4096 * 2;
    u16* attn  = (u16*)p; p += BS * 1024 * 2;
    float* rrow = (float*)p; p += (long)Z * 4096L * 4;

    // 1. conversions / weight transposes
    k_cvt_f32_bf16<<<dim3((unsigned)(BS * 2048 / 2048)), 256, 0, stream>>>(x_f, x_bf, BS * 2048);
    k_transpose_bf16<float><<<dim3(3072 / 32, 2048 / 32, 1), dim3(32, 8), 0, stream>>>(
        Wqkv_f, 3072, 0, WqkvT, 2048, 0, 2048, 3072);
    k_transpose_bf16<float><<<dim3(1024 / 32, 1024 / 32, 1), dim3(32, 8), 0, stream>>>(
        Wff_f, 1024, 0, WffT, 1024, 0, 1024, 1024);

    // 2. kqv = X @ W_qkv   [16384 x 3072], K=2048
    k_gemm3b<0><<<dim3(3072 / 256, 16384 / 128, 1), 512, 0, stream>>>(
        x_bf, 2048, 0, WqkvT, 2048, 0, kqv, 3072, 0, 2048, 0.f, nullptr, 0, nullptr);

    // 3. transpose V (cols [2048,3072) of kqv) to [4][1024][4096]
    k_transpose_bf16<u16><<<dim3(1024 / 32, 4096 / 32, 4), dim3(32, 8), 0, stream>>>(
        kqv + 2048, 3072, (long)S * 3072, vT, 4096, 1024L * 4096, 4096, 1024);

    // 4. attention: probs = exp(Q K^T * scale); attn = (probs @ V) * (1/rowsum)
    const float scale = 0.08838834764831845f;  // 1/sqrt(128)
    for (int b = 0; b < 4; b += Z) {
        const u16* kbase = kqv + (long)b * S * 3072;  // k at +0, q at +1024
        k_gemm3b<1><<<dim3(4096 / 256, 4096 / 128, Z), 512, 0, stream>>>(
            kbase + 1024, 3072, (long)S * 3072, kbase, 3072, (long)S * 3072,
            probs, 4096, (long)S * S, 1024, scale, nullptr, 0, nullptr);
        k_rowsum_recip<<<Z * 4096, 256, 0, stream>>>(probs, rrow, 4096);
        k_gemm3b<2><<<dim3(1024 / 256, 4096 / 128, Z), 512, 0, stream>>>(
            probs, 4096, (long)S * S, vT + (long)b * 1024 * 4096, 4096, 1024L * 4096,
            attn + (long)b * S * 1024, 1024, (long)S * 1024,
            4096, 0.f, rrow, 4096, nullptr);
    }

    // 5. out = attn @ W_ff + b_ff  (fp32 output)
    k_gemm3b<3><<<dim3(1024 / 256, 16384 / 128, 1), 512, 0, stream>>>(
        attn, 1024, 0, WffT, 1024, 0, out, 1024, 0, 1024, 0.f, nullptr, 0, bff);
}

// Round 7
// 618.393 us; speedup vs baseline: 1.2052x; 1.0012x over previous
//
#include <hip/hip_runtime.h>

typedef unsigned short u16;
using bf16x8 = __attribute__((ext_vector_type(8))) __bf16;
using f32x4  = __attribute__((ext_vector_type(4))) float;
using u16x8  = __attribute__((ext_vector_type(8))) u16;

__device__ __forceinline__ u16 f2bf(float f) {
    unsigned u = __builtin_bit_cast(unsigned, f);
    u += 0x7FFFu + ((u >> 16) & 1u);           // round-to-nearest-even
    return (u16)(u >> 16);
}
__device__ __forceinline__ float bf2f(u16 h) {
    unsigned u = ((unsigned)h) << 16;
    return __builtin_bit_cast(float, u);
}
__device__ __forceinline__ u16 to_bf(float f) { return f2bf(f); }
__device__ __forceinline__ u16 to_bf(u16 h)   { return h; }

// async global->LDS, 16B per lane; LDS base must be wave-uniform.
__device__ __forceinline__ void gload_lds16(const u16* g, u16* l) {
    __builtin_amdgcn_global_load_lds(
        (const __attribute__((address_space(1))) unsigned int*)g,
        (__attribute__((address_space(3))) unsigned int*)l,
        16, 0, 0);
}

// ---------------- fp32 -> bf16 elementwise (vectorized) ----------------
__global__ __launch_bounds__(256) void k_cvt_f32_bf16(const float* __restrict__ in,
                                                      u16* __restrict__ out, long n) {
    long i = ((long)blockIdx.x * 256 + threadIdx.x) * 8;
    if (i + 8 > n) return;
    f32x4 a = *(const f32x4*)(in + i);
    f32x4 b = *(const f32x4*)(in + i + 4);
    u16x8 o;
    o[0] = f2bf(a[0]); o[1] = f2bf(a[1]); o[2] = f2bf(a[2]); o[3] = f2bf(a[3]);
    o[4] = f2bf(b[0]); o[5] = f2bf(b[1]); o[6] = f2bf(b[2]); o[7] = f2bf(b[3]);
    *(u16x8*)(out + i) = o;
}

// ---------------- tiled transpose (f32->bf16 or bf16->bf16) ----------------
template <typename T>
__global__ __launch_bounds__(256) void k_transpose_bf16(
    const T* __restrict__ in, long in_rs, long in_bs,
    u16* __restrict__ out, long out_rs, long out_bs, int R, int C) {
    __shared__ u16 tile[32][33];
    const int b = blockIdx.z;
    const T* ip = in + (long)b * in_bs;
    u16* op = out + (long)b * out_bs;
    const int tx = threadIdx.x, ty = threadIdx.y;
    const long r0 = (long)blockIdx.y * 32, c0 = (long)blockIdx.x * 32;
#pragma unroll
    for (int i = 0; i < 4; ++i) {
        int r = ty + i * 8;
        tile[r][tx] = to_bf(ip[(r0 + r) * in_rs + c0 + tx]);
    }
    __syncthreads();
#pragma unroll
    for (int i = 0; i < 4; ++i) {
        int c = ty + i * 8;
        op[(c0 + c) * out_rs + r0 + tx] = tile[tx][c];
    }
}

// --------- reduce per-block partial row sums -> reciprocal ----------
// psum: [Z][nx][4096] (written by QK^T blocks), rrow: [Z][4096]
__global__ __launch_bounds__(256) void k_psum_recip(const float* __restrict__ psum,
                                                    float* __restrict__ rrow,
                                                    int nx, long total) {
    long idx = (long)blockIdx.x * 256 + threadIdx.x;
    if (idx >= total) return;
    const long z = idx >> 12, row = idx & 4095;
    const float* p = psum + (z * nx) * 4096 + row;
    float s = 0.f;
    for (int x = 0; x < nx; ++x) s += p[(long)x * 4096];
    rrow[idx] = 1.0f / s;
}

// ====== 128x256 bf16 GEMM, BK=32, 3-buffer ring, 2 blocks/CU, C = A*B^T ======
// A: [M][K] (lda), B: [N][K] (ldb). M mult of 128, N of 256, K of 32 (NT>=3).
// 8 waves (2M x 4N), per-wave 64x64 output. LDS 72 KB -> 2 blocks/CU.
// Swizzle byte ^= ((byte>>9)&1)<<5 on both sides (verified 0 conflicts).
// Tile body: 8 ds_read_b128 + stage tile t+2 + 16 MFMA with NO manual lgkmcnt
// drain — the compiler emits fine-grained counted lgkmcnt so reads pipeline
// into the MFMA burst (m97/m141 lesson: manual full-drain defeats this).
// Collective staging visibility: counted vmcnt ("memory" asm fences motion)
// before the per-tile s_barrier; vmcnt(3) steady state (never 0 mid-loop).
// EPI 0: bf16(acc)  1: bf16(exp(acc*scale)) + per-block row-sum partials
// EPI 2: bf16(acc*rrow[row])  3: f32(acc+bias[col])

#define VMC(n) asm volatile("s_waitcnt vmcnt(" #n ")" ::: "memory")
#define SCHB   __builtin_amdgcn_sched_barrier(0)
#define BAR    __builtin_amdgcn_s_barrier()
#define PRIO1  __builtin_amdgcn_s_setprio(1)
#define PRIO0  __builtin_amdgcn_s_setprio(0)
#define SWZ(b) ((b) ^ ((((b) >> 9) & 1) << 5))

template <int EPI>
__global__ __launch_bounds__(512, 4) void k_gemm3b(
    const u16* __restrict__ Ag, long lda, long sA,
    const u16* __restrict__ Bg, long ldb, long sB,
    void* __restrict__ Cv, long ldc, long sC,
    int K, float scale, const float* __restrict__ rrowZ, long sR,
    const float* __restrict__ bias, float* __restrict__ psum) {
    __shared__ __align__(16) u16 As[3][128 * 32];
    __shared__ __align__(16) u16 Bs[3][256 * 32];

    const int tid = threadIdx.x;
    const int lane = tid & 63, wid = tid >> 6;
    const int wm = wid >> 2, wn = wid & 3;   // 2(M) x 4(N) wave grid
    const int z = blockIdx.z;
    const long m0 = (long)blockIdx.y * 128;
    const long n0 = (long)blockIdx.x * 256;
    const u16* A = Ag + (long)z * sA;
    const u16* B = Bg + (long)z * sB;

    // staging sources (linear LDS dest; pre-swizzled global src).
    long aSrc, bSrc0, bSrc1;
    {
        int dg = SWZ(tid * 16);
        aSrc = (m0 + (dg >> 6)) * lda + ((dg & 63) >> 1);
        bSrc0 = (n0 + (dg >> 6)) * ldb + ((dg & 63) >> 1);
        dg = SWZ(8192 + tid * 16);
        bSrc1 = (n0 + (dg >> 6)) * ldb + ((dg & 63) >> 1);
    }
    const int r16 = lane & 15, g = lane >> 4;
    const int vA = SWZ((wm * 64 + r16) * 64 + g * 16);   // byte off in A buf
    const int vB = SWZ((wn * 64 + r16) * 64 + g * 16);   // byte off in B buf

#define STG(bb, kt) do { \
        gload_lds16(A + aSrc + (kt), &As[bb][wid * 512]); \
        gload_lds16(B + bSrc0 + (kt), &Bs[bb][wid * 512]); \
        gload_lds16(B + bSrc1 + (kt), &Bs[bb][4096 + wid * 512]); } while (0)
#define LD4_A(bb) do { _Pragma("unroll") for (int _i = 0; _i < 4; ++_i) \
        afr[_i] = *(const bf16x8*)((const char*)&As[bb][0] + vA + _i * 1024); } while (0)
#define LD4_B(bb) do { _Pragma("unroll") for (int _i = 0; _i < 4; ++_i) \
        bfr[_i] = *(const bf16x8*)((const char*)&Bs[bb][0] + vB + _i * 1024); } while (0)
#define MM16() do { \
        _Pragma("unroll") for (int mf = 0; mf < 4; ++mf) \
        _Pragma("unroll") for (int nf = 0; nf < 4; ++nf) \
            acc[mf][nf] = __builtin_amdgcn_mfma_f32_16x16x32_bf16( \
                afr[mf], bfr[nf], acc[mf][nf], 0, 0, 0); } while (0)

    f32x4 acc[4][4] = {};
    bf16x8 afr[4], bfr[4];

    const int NT = K >> 5;   // K-tiles of 32; NT >= 3 assumed
    // prologue: stage tiles 0 and 1
    STG(0, 0); STG(1, 32);
    VMC(3); SCHB;            // tile 0's 3 loads landed (own); BAR -> collective
    BAR; SCHB;

    int b0 = 0, b1 = 1, b2 = 2;
    for (int t = 0; t < NT; ++t) {
        LD4_A(b0); LD4_B(b0);                       // 8 ds_read_b128
        if (t + 2 < NT) STG(b2, (long)(t + 2) * 32);
        PRIO1; MM16(); PRIO0;                       // compiler-counted lgkmcnt
        if (t + 2 < NT) { VMC(3); }                 // retire tile t+1's loads
        else if (t + 1 < NT) { VMC(0); }            // tail drain
        BAR; SCHB;
        int tm = b0; b0 = b1; b1 = b2; b2 = tm;
    }

    // epilogue. C/D layout: col = lane&15, row = (lane>>4)*4 + j
    const int r_in = (lane >> 4) * 4;
    const int c_in = lane & 15;
    const float* rr = (EPI == 2) ? (rrowZ + (long)z * sR) : nullptr;
    float rsum[4][4];
    if constexpr (EPI == 1) {
#pragma unroll
        for (int a = 0; a < 4; ++a)
#pragma unroll
            for (int b = 0; b < 4; ++b) rsum[a][b] = 0.f;
    }
#pragma unroll
    for (int mf = 0; mf < 4; ++mf) {
#pragma unroll
        for (int nf = 0; nf < 4; ++nf) {
            const long cg = n0 + wn * 64 + nf * 16 + c_in;
#pragma unroll
            for (int j = 0; j < 4; ++j) {
                const long rg = m0 + wm * 64 + mf * 16 + r_in + j;
                float v = acc[mf][nf][j];
                if constexpr (EPI == 0) {
                    ((u16*)Cv)[(long)z * sC + rg * ldc + cg] = f2bf(v);
                } else if constexpr (EPI == 1) {
                    float e = __expf(v * scale);
                    ((u16*)Cv)[(long)z * sC + rg * ldc + cg] = f2bf(e);
                    rsum[mf][j] += e;
                } else if constexpr (EPI == 2) {
                    ((u16*)Cv)[(long)z * sC + rg * ldc + cg] = f2bf(v * rr[rg]);
                } else {
                    ((float*)Cv)[(long)z * sC + rg * ldc + cg] = v + bias[cg];
                }
            }
        }
    }
    if constexpr (EPI == 1) {
        // per-block partial row sums -> psum[(z*gridDim.x + bx)*M + m0 + row]
        float* ps = (float*)&As[0][0];   // [128][4] scratch (staging LDS is dead)
#pragma unroll
        for (int mf = 0; mf < 4; ++mf) {
#pragma unroll
            for (int j = 0; j < 4; ++j) {
                float s = rsum[mf][j];
#pragma unroll
                for (int w = 1; w < 16; w <<= 1) s += __shfl_xor(s, w);
                if ((lane & 15) == 0)
                    ps[(wm * 64 + mf * 16 + (lane >> 4) * 4 + j) * 4 + wn] = s;
            }
        }
        __syncthreads();
        if (tid < 128) {
            float s = ps[tid * 4] + ps[tid * 4 + 1] + ps[tid * 4 + 2] + ps[tid * 4 + 3];
            const long M = (long)gridDim.y * 128;
            psum[((long)z * gridDim.x + blockIdx.x) * M + m0 + tid] = s;
        }
    }
#undef MM16
#undef LD4_A
#undef LD4_B
#undef STG
}

extern "C" void kernel_launch(void* const* d_in, const int* in_sizes, int n_in,
                              void* d_out, int out_size, void* d_ws, size_t ws_size,
                              hipStream_t stream) {
    (void)in_sizes; (void)n_in; (void)out_size;
    const int S = 4096;
    const long BS = 4L * S;  // 16384 tokens
    const float* x_f    = (const float*)d_in[0];  // [BS][2048]
    const float* Wqkv_f = (const float*)d_in[1];  // [2048][3072]
    const float* Wff_f  = (const float*)d_in[2];  // [1024][1024]
    const float* bff    = (const float*)d_in[3];  // [1024]
    float* out = (float*)d_out;                   // [BS][1024]

    // batched attention (z=4) needs 4x probs; fall back if ws too small
    const size_t need4 = 67108864UL + 12582912UL + 2097152UL + 100663296UL +
                         33554432UL + 4UL * 33554432UL + 33554432UL + 65536UL +
                         4UL * 16 * 4096 * 4;
    const bool batched = ws_size >= need4;
    const int Z = batched ? 4 : 1;

    char* p = (char*)d_ws;
    u16* x_bf  = (u16*)p; p += BS * 2048 * 2;
    u16* WqkvT = (u16*)p; p += 3072L * 2048 * 2;
    u16* WffT  = (u16*)p; p += 1024L * 1024 * 2;
    u16* kqv   = (u16*)p; p += BS * 3072 * 2;
    u16* vT    = (u16*)p; p += 4L * 1024 * 4096 * 2;
    u16* probs = (u16*)p; p += (long)Z * 4096L * 4096 * 2;
    u16* attn  = (u16*)p; p += BS * 1024 * 2;
    float* rrow = (float*)p; p += (long)Z * 4096L * 4;
    float* psum = (float*)p; p += (long)Z * 16 * 4096 * 4;

    // 1. conversions / weight transposes
    k_cvt_f32_bf16<<<dim3((unsigned)(BS * 2048 / 2048)), 256, 0, stream>>>(x_f, x_bf, BS * 2048);
    k_transpose_bf16<float><<<dim3(3072 / 32, 2048 / 32, 1), dim3(32, 8), 0, stream>>>(
        Wqkv_f, 3072, 0, WqkvT, 2048, 0, 2048, 3072);
    k_transpose_bf16<float><<<dim3(1024 / 32, 1024 / 32, 1), dim3(32, 8), 0, stream>>>(
        Wff_f, 1024, 0, WffT, 1024, 0, 1024, 1024);

    // 2. kqv = X @ W_qkv   [16384 x 3072], K=2048
    k_gemm3b<0><<<dim3(3072 / 256, 16384 / 128, 1), 512, 0, stream>>>(
        x_bf, 2048, 0, WqkvT, 2048, 0, kqv, 3072, 0, 2048, 0.f, nullptr, 0, nullptr, nullptr);

    // 3. transpose V (cols [2048,3072) of kqv) to [4][1024][4096]
    k_transpose_bf16<u16><<<dim3(1024 / 32, 4096 / 32, 4), dim3(32, 8), 0, stream>>>(
        kqv + 2048, 3072, (long)S * 3072, vT, 4096, 1024L * 4096, 4096, 1024);

    // 4. attention: probs = exp(Q K^T * scale) with fused row-sum partials;
    //    attn = (probs @ V) * (1/rowsum)
    const float scale = 0.08838834764831845f;  // 1/sqrt(128)
    for (int b = 0; b < 4; b += Z) {
        const u16* kbase = kqv + (long)b * S * 3072;  // k at +0, q at +1024
        k_gemm3b<1><<<dim3(4096 / 256, 4096 / 128, Z), 512, 0, stream>>>(
            kbase + 1024, 3072, (long)S * 3072, kbase, 3072, (long)S * 3072,
            probs, 4096, (long)S * S, 1024, scale, nullptr, 0, nullptr, psum);
        k_psum_recip<<<(Z * 4096 + 255) / 256, 256, 0, stream>>>(
            psum, rrow, 16, (long)Z * 4096);
        k_gemm3b<2><<<dim3(1024 / 256, 4096 / 128, Z), 512, 0, stream>>>(
            probs, 4096, (long)S * S, vT + (long)b * 1024 * 4096, 4096, 1024L * 4096,
            attn + (long)b * S * 1024, 1024, (long)S * 1024,
            4096, 0.f, rrow, 4096, nullptr, nullptr);
    }

    // 5. out = attn @ W_ff + b_ff  (fp32 output)
    k_gemm3b<3><<<dim3(1024 / 256, 16384 / 128, 1), 512, 0, stream>>>(
        attn, 1024, 0, WffT, 1024, 0, out, 1024, 0, 1024, 0.f, nullptr, 0, bff, nullptr);
}